// Round 4
// baseline (391.573 us; speedup 1.0000x reference)
//
#include <hip/hip_runtime.h>
#include <hip/hip_bf16.h>

// ChebyKAN: y[b,o] = sum_{i,d} T_d(tanh(x[b,i])) * W[i,o,d]
// GEMM M=16384, N=1024, K=9216 with generated A (packed-fp16 Chebyshev recurrence).
// R4: fixes R3's cross-wave race: per-wave counted vmcnt must come BEFORE
//     s_barrier (each wave proves its stage retired at the rendezvous).
//     Order per phase: wait(counted) -> barrier -> issue depth-2 stage -> compute.
//     9 LDS step-buffers (72KB) so depth-2 never overwrites the set being read.

#define WSCALE 4096.0f
#define INV_WSCALE (1.0f/4096.0f)

typedef _Float16 f16;
typedef _Float16 f16x8 __attribute__((ext_vector_type(8)));
typedef float    f32x4 __attribute__((ext_vector_type(4)));
typedef float    f32x16 __attribute__((ext_vector_type(16)));

// ---- kernel 1: repack cc [I][O][9] f32 -> wt [9][I/32][O][32] f16 (x4096),
//      16B-slot XOR swizzle baked in: slot u of row o holds k-group u ^ ((o>>1)&3).
__global__ __launch_bounds__(256) void wt_transform(const float* __restrict__ cc,
                                                    f16* __restrict__ wt) {
  int gid = blockIdx.x * 256 + threadIdx.x;   // 9*32*1024 threads
  int o   = gid & 1023;
  int t2  = gid >> 10;
  int ic  = t2 & 31;          // i-chunk (32 i's)
  int d   = t2 >> 5;          // 0..8
  int f   = (o >> 1) & 3;     // swizzle key
  const size_t rowbase = ((size_t)(d * 32 + ic) * 1024 + o) * 32;
#pragma unroll
  for (int u = 0; u < 4; ++u) {
    int kg = u ^ f;           // k-group stored at slot u
    f16x8 v;
#pragma unroll
    for (int e = 0; e < 8; ++e) {
      int i = ic * 32 + kg * 8 + e;
      v[e] = (f16)(cc[((size_t)i * 1024 + o) * 9 + d] * WSCALE);
    }
    *(f16x8*)(wt + rowbase + u * 8) = v;
  }
}

// ---- kernel 2: fused basis-gen + GEMM, 128x128 tile, 4 waves (2x2), wave 64x64
__global__ __launch_bounds__(256, 2) void cheby_gemm(const float* __restrict__ x,
                                                     const f16* __restrict__ wt,
                                                     float* __restrict__ out) {
  __shared__ f16 bbuf[9][4096];               // buffer per degree: 9 x 8KB = 72KB

  const int tid  = threadIdx.x;
  const int wid  = tid >> 6;
  const int lane = tid & 63;
  const int lr   = lane & 31;                 // row/col within 32-block
  const int lh   = lane >> 5;                 // k-subgroup select
  const int wr   = wid >> 1, wc = wid & 1;
  const int mrow = blockIdx.x >> 3;
  const int ncol = blockIdx.x & 7;            // == XCD id round-robin: wt slice L2-resident
  const int m0   = mrow * 128 + wr * 64;
  const int n0   = ncol * 128 + wc * 64;
  const int nc128 = ncol * 128;

  auto stage = [&](int cn, int dn, int buf) {
    const f16* src = wt + ((size_t)(dn * 32 + cn) * 1024 + nc128) * 32;
    __builtin_amdgcn_global_load_lds(
        (const __attribute__((address_space(1))) unsigned*)(src + tid * 8),
        (__attribute__((address_space(3))) unsigned*)(&bbuf[buf][wid * 512]),
        16, 0, 0);
    __builtin_amdgcn_global_load_lds(
        (const __attribute__((address_space(1))) unsigned*)(src + 2048 + tid * 8),
        (__attribute__((address_space(3))) unsigned*)(&bbuf[buf][wid * 512 + 2048]),
        16, 0, 0);
  };
  auto stage3 = [&](int cn, int dn0, int b0) {
    stage(cn, dn0, b0); stage(cn, dn0 + 1, b0 + 1); stage(cn, dn0 + 2, b0 + 2);
  };

  f32x16 acc[2][2];
#pragma unroll
  for (int a = 0; a < 2; ++a)
#pragma unroll
    for (int b = 0; b < 2; ++b)
#pragma unroll
      for (int j = 0; j < 16; ++j) acc[a][b][j] = 0.f;

  const f16x8 ones  = {(f16)1,(f16)1,(f16)1,(f16)1,(f16)1,(f16)1,(f16)1,(f16)1};
  const f16x8 half8 = {(f16)0.5f,(f16)0.5f,(f16)0.5f,(f16)0.5f,
                       (f16)0.5f,(f16)0.5f,(f16)0.5f,(f16)0.5f};
  f16x8 Tm1[2][2], Tm2[2][2], t2v[2][2], t2n[2][2];
  f32x4 xf[2][2][2];

  auto loadx = [&](int cn) {   // 8 VMEM instrs
#pragma unroll
    for (int mb = 0; mb < 2; ++mb)
#pragma unroll
      for (int h = 0; h < 2; ++h) {
        const float* p = x + (size_t)(m0 + mb * 32 + lr) * 1024 + cn * 32 + h * 16 + lh * 8;
        xf[mb][h][0] = *(const f32x4*)p;
        xf[mb][h][1] = *(const f32x4*)(p + 4);
      }
  };
  auto dotanh = [&]() {        // xf -> t2n = 2*tanh(x) (f16, exact x2)
#pragma unroll
    for (int mb = 0; mb < 2; ++mb)
#pragma unroll
      for (int h = 0; h < 2; ++h) {
        f16x8 tv;
#pragma unroll
        for (int e = 0; e < 8; ++e) {
          float xx = (e < 4) ? xf[mb][h][0][e] : xf[mb][h][1][e - 4];
          float t  = 1.f - 2.f * __builtin_amdgcn_rcpf(__expf(2.f * xx) + 1.f);
          tv[e] = (f16)t;
        }
        t2n[mb][h] = tv + tv;
      }
  };

// one degree: recurrence -> A frags, read B frags from bbuf[D], 8 MFMAs
#define DO_DEG(D)                                                              \
  {                                                                            \
    f16x8 af[2][2];                                                            \
    if ((D) == 0) {                                                            \
      _Pragma("unroll") for (int mb = 0; mb < 2; ++mb)                         \
        _Pragma("unroll") for (int h = 0; h < 2; ++h) af[mb][h] = ones;        \
    } else if ((D) == 1) {                                                     \
      _Pragma("unroll") for (int mb = 0; mb < 2; ++mb)                         \
        _Pragma("unroll") for (int h = 0; h < 2; ++h) {                        \
          f16x8 t1 = t2v[mb][h] * half8;                                       \
          Tm1[mb][h] = t1; Tm2[mb][h] = ones; af[mb][h] = t1;                  \
        }                                                                      \
    } else {                                                                   \
      _Pragma("unroll") for (int mb = 0; mb < 2; ++mb)                         \
        _Pragma("unroll") for (int h = 0; h < 2; ++h) {                        \
          f16x8 tn = __builtin_elementwise_fma(t2v[mb][h], Tm1[mb][h], -Tm2[mb][h]); \
          Tm2[mb][h] = Tm1[mb][h]; Tm1[mb][h] = tn; af[mb][h] = tn;            \
        }                                                                      \
    }                                                                          \
    const f16* bb = &bbuf[(D)][0];                                             \
    f16x8 bf[2][2];                                                            \
    _Pragma("unroll") for (int nb = 0; nb < 2; ++nb)                           \
      _Pragma("unroll") for (int h = 0; h < 2; ++h) {                          \
        int ol = wc * 64 + nb * 32 + lr;                                       \
        int slot = ((h << 1) | lh) ^ ((ol >> 1) & 3);                          \
        bf[nb][h] = *(const f16x8*)&bb[ol * 32 + slot * 8];                    \
      }                                                                        \
    __builtin_amdgcn_s_setprio(1);                                             \
    _Pragma("unroll") for (int mb = 0; mb < 2; ++mb)                           \
      _Pragma("unroll") for (int nb = 0; nb < 2; ++nb) {                       \
        acc[mb][nb] = __builtin_amdgcn_mfma_f32_32x32x16_f16(af[mb][0], bf[nb][0], \
                                                             acc[mb][nb], 0, 0, 0); \
        acc[mb][nb] = __builtin_amdgcn_mfma_f32_32x32x16_f16(af[mb][1], bf[nb][1], \
                                                             acc[mb][nb], 0, 0, 0); \
      }                                                                        \
    __builtin_amdgcn_s_setprio(0);                                             \
  }

  // prologue: stage chunk0 deg 0-2 (set0) + deg 3-5 (set1), load+tanh chunk0 x
  stage3(0, 0, 0);
  stage3(0, 3, 3);
  loadx(0);
  dotanh();

  for (int c = 0; c < 32; ++c) {
    const bool lastc = (c == 31);

    // ---- phase q0: degrees 0,1,2 (bufs 0-2; staged 2 phases ago)
    // own-vmcnt proof BEFORE barrier: after stage3(deg0-2) came stage3(deg3-5)
    // [6]; x-loads ordering-insensitive -> N=6 always valid.
    asm volatile("s_waitcnt vmcnt(6)" ::: "memory");
    __builtin_amdgcn_s_barrier();
    stage3(c, 6, 6);                        // deg 6-8 chunk c -> bufs 6-8
#pragma unroll
    for (int mb = 0; mb < 2; ++mb)
#pragma unroll
      for (int h = 0; h < 2; ++h) t2v[mb][h] = t2n[mb][h];  // adopt chunk c tanh
    DO_DEG(0) DO_DEG(1) DO_DEG(2)

    // ---- phase q1: degrees 3,4,5 (bufs 3-5)
    // after stage3(deg3-5)@prev-q2: stage3(deg6-8)@q0 [6] -> N=6
    asm volatile("s_waitcnt vmcnt(6)" ::: "memory");
    __builtin_amdgcn_s_barrier();
    if (!lastc) {
      stage3(c + 1, 0, 0);                  // deg 0-2 chunk c+1 -> bufs 0-2
      loadx(c + 1);                         // 8 VMEM, tanh'd next phase
    }
    DO_DEG(3) DO_DEG(4) DO_DEG(5)

    // ---- phase q2: degrees 6,7,8 (bufs 6-8)
    // after stage3(deg6-8)@q0: q1 issued stage3[6] + loadx[8] -> N=14
    if (lastc) asm volatile("s_waitcnt vmcnt(0)" ::: "memory");
    else       asm volatile("s_waitcnt vmcnt(14)" ::: "memory");
    __builtin_amdgcn_s_barrier();
    if (!lastc) {
      stage3(c + 1, 3, 3);                  // deg 3-5 chunk c+1 -> bufs 3-5
      dotanh();                             // chunk c+1 seed (compiler waits xf)
    }
    DO_DEG(6) DO_DEG(7) DO_DEG(8)
  }
#undef DO_DEG

  // epilogue: 32x32 C/D map: col = lane&31, row = (j&3) + 8*(j>>2) + 4*(lane>>5)
#pragma unroll
  for (int mb = 0; mb < 2; ++mb)
#pragma unroll
    for (int nb = 0; nb < 2; ++nb)
#pragma unroll
      for (int j = 0; j < 16; ++j) {
        int row = m0 + mb * 32 + 4 * lh + (j & 3) + 8 * (j >> 2);
        int col = n0 + nb * 32 + lr;
        out[(size_t)row * 1024 + col] = acc[mb][nb][j] * INV_WSCALE;
      }
}

extern "C" void kernel_launch(void* const* d_in, const int* in_sizes, int n_in,
                              void* d_out, int out_size, void* d_ws, size_t ws_size,
                              hipStream_t stream) {
  const float* x  = (const float*)d_in[0];
  const float* cc = (const float*)d_in[1];
  f16*   wt  = (f16*)d_ws;                // 9*32*1024*32*2 = 18,874,368 B
  float* out = (float*)d_out;

  hipLaunchKernelGGL(wt_transform, dim3(1152), dim3(256), 0, stream, cc, wt);
  hipLaunchKernelGGL(cheby_gemm, dim3(1024), dim3(256), 0, stream, x, wt, out);
}